// Round 14
// baseline (99.221 us; speedup 1.0000x reference)
//
#include <hip/hip_runtime.h>
#include <hip/hip_bf16.h>
#include <utility>

// Problem constants (fixed by the reference setup_inputs()).
#define J_     24
#define CIN_   32
#define COUT_  32
#define B_     8
#define T_     4096
#define R_     12
#define TT_    128                         // t per main-kernel block (4 t-slices x 32t, x2 joints = 8 waves)
#define POOLED_SZ_ (B_ * R_ * COUT_ * T_)  // 12,582,912
#define XT_ELEMS_  ((size_t)B_ * T_ * (J_ * CIN_))   // 25,165,824 bf16
#define NFRAG_     420                     // 70 edges * 3 kw * 2 K-halves
#define PLROWS_    145                     // rows per ci-plane (145*16B = 2320 B, != 0 mod 32 dw)
#define PLSTR_     (PLROWS_ * 16)          // 2320 B plane stride
#define BSLAB_     (4 * PLSTR_)            // 9280 B per neighbor slab
#define ALDS_      49152                   // A-fragment LDS region (48 KB)

typedef float  f32x4  __attribute__((ext_vector_type(4)));
typedef float  f32x16 __attribute__((ext_vector_type(16)));
typedef short  bf16x8 __attribute__((ext_vector_type(8)));
typedef unsigned short us8 __attribute__((ext_vector_type(8)));

// Compile-time adjacency (verified R1/R5): bit n of kAdjMask[i] <=> n in ADJ_LIST[i].
static constexpr unsigned kAdjMask[J_] = {
    0x0000000Fu, 0x00000013u, 0x00000025u, 0x00000049u, 0x00000092u, 0x00000124u,
    0x00000248u, 0x00000490u, 0x00000920u, 0x00007240u, 0x00000480u, 0x00000900u,
    0x00009200u, 0x00012200u, 0x00024200u, 0x00009000u, 0x00052000u, 0x000A4000u,
    0x00150000u, 0x002A0000u, 0x00540000u, 0x00A80000u, 0x00500000u, 0x00A00000u
};
static constexpr int kAdjOff[J_ + 1] = {
    0,4,7,10,13,16,19,22,25,28,33,35,37,40,43,46,48,51,54,57,60,63,66,68,70
};
static constexpr int edge_of(int jout, int nb) {
    return kAdjOff[jout] + __builtin_popcount(kAdjMask[jout] & ((1u << nb) - 1u));
}
static constexpr int nedges(int j) { return kAdjOff[j + 1] - kAdjOff[j]; }
// LDS slot base (in 1KB frags) for edge (2*RGN+js -> nb): j0's edges first, then j1's.
static constexpr int local_base(int RGN, int js, int nb) {
    const int j = 2 * RGN + js;
    const int within = edge_of(j, nb) - kAdjOff[j];
    const int pre = js ? nedges(2 * RGN) : 0;
    return (pre + within) * 6;
}
// Union-neighborhood helpers.
static constexpr unsigned union_mask(int r) { return kAdjMask[2 * r] | kAdjMask[2 * r + 1]; }
static constexpr int union_rank(int r, int nb) {
    return __builtin_popcount(union_mask(r) & ((1u << nb) - 1u));
}

// Device-side tables for runtime staging / pack kernels.
__device__ __constant__ unsigned int ADJMASK[J_] = {
    0x0000000Fu, 0x00000013u, 0x00000025u, 0x00000049u, 0x00000092u, 0x00000124u,
    0x00000248u, 0x00000490u, 0x00000920u, 0x00007240u, 0x00000480u, 0x00000900u,
    0x00009200u, 0x00012200u, 0x00024200u, 0x00009000u, 0x00052000u, 0x000A4000u,
    0x00150000u, 0x002A0000u, 0x00540000u, 0x00A80000u, 0x00500000u, 0x00A00000u
};
__device__ __constant__ int ADJ_FLAT[70] = {
    0,1,2,3,  0,1,4,  0,2,5,  0,3,6,  1,4,7,  2,5,8,  3,6,9,  4,7,10,  5,8,11,
    6,9,12,13,14,  7,10,  8,11,  9,12,15,  9,13,16,  9,14,17,  12,15,
    13,16,18,  14,17,19,  16,18,20,  17,19,21,  18,20,22,  19,21,23,  20,22,  21,23
};
__device__ __constant__ int ADJ_OFF[J_ + 1] = {
    0,4,7,10,13,16,19,22,25,28,33,35,37,40,43,46,48,51,54,57,60,63,66,68,70
};
// Union walk tables (ascending; verified against kAdjMask ORs).
__device__ __constant__ int UNION_CNT[R_] = {5,5,6,6,8,4,5,5,6,6,6,4};
__device__ __constant__ int UNION_NB[R_][8] = {
    {0,1,2,3,4,0,0,0},      {0,2,3,5,6,0,0,0},      {1,2,4,5,7,8,0,0},
    {3,4,6,7,9,10,0,0},     {5,6,8,9,11,12,13,14},  {7,8,10,11,0,0,0,0},
    {9,12,13,15,16,0,0,0},  {9,12,14,15,17,0,0,0},  {13,14,16,17,18,19,0,0},
    {16,17,18,19,20,21,0,0},{18,19,20,21,22,23,0,0},{20,21,22,23,0,0,0,0}
};

static __device__ __forceinline__ unsigned short f2bf(float f) {
    unsigned u = __float_as_uint(f);
    unsigned r = (u + 0x7fffu + ((u >> 16) & 1u)) >> 16;   // RNE
    return (unsigned short)r;
}

// Async global->LDS, 16 B per lane. LDS dest is wave-uniform; source is per-lane.
static __device__ __forceinline__ void gload_lds16(const void* g, void* l) {
    __builtin_amdgcn_global_load_lds(
        (const __attribute__((address_space(1))) unsigned int*)g,
        (__attribute__((address_space(3))) unsigned int*)l, 16, 0, 0);
}

// ---------------------------------------------------------------------------
// Pre-kernel 1: x fp32 [b][768][4096] -> xT bf16 [b][4096][768] via LDS tiles.
// (Already ~HBM-roofline: 148 MB at ~6 TB/s.)
// ---------------------------------------------------------------------------
__global__ __launch_bounds__(256)
void skel_transpose(const float* __restrict__ x, unsigned short* __restrict__ xT)
{
    __shared__ float xs[32][257];
    const int tid = threadIdx.x;
    const int tt0 = blockIdx.x * 256;   // t tile
    const int cg  = blockIdx.y;         // channel group of 32 (0..23)
    const int b   = blockIdx.z;

    const float* xp = x + ((size_t)b * (J_ * CIN_) + cg * 32) * T_ + tt0;
#pragma unroll
    for (int i = 0; i < 8; ++i) {
        const int idx = tid + i * 256;
        const int row = idx >> 6;            // 0..31
        const int c4  = (idx & 63) << 2;     // 0..252
        const float4 v = *(const float4*)(xp + (size_t)row * T_ + c4);
        xs[row][c4 + 0] = v.x; xs[row][c4 + 1] = v.y;
        xs[row][c4 + 2] = v.z; xs[row][c4 + 3] = v.w;
    }
    __syncthreads();

    union { unsigned short u[32]; uint4 q[4]; } pk;
#pragma unroll
    for (int c = 0; c < 32; ++c) pk.u[c] = f2bf(xs[c][tid]);
    unsigned short* dst = xT + ((size_t)b * T_ + tt0 + tid) * (J_ * CIN_) + cg * 32;
#pragma unroll
    for (int k = 0; k < 4; ++k) *(uint4*)(dst + k * 8) = pk.q[k];
}

// ---------------------------------------------------------------------------
// Pre-kernel 2: pack masked W blocks into per-lane 32x32x16 MFMA A-fragments.
// Lane map: m(co) = lane&31; k(ci) = h*16 + (lane>>5)*8 + j  -- SAME
// (lane-group, j)->ci map as the B side, so internal K permutation cancels.
// Block 420 additionally writes the REGIONS / POST_ADJ constant outputs.
// ---------------------------------------------------------------------------
__global__ __launch_bounds__(64)
void skel_pack(const float* __restrict__ W, unsigned short* __restrict__ wsW,
               float* __restrict__ out_regions, float* __restrict__ out_post)
{
    const int fb = blockIdx.x;
    const int l  = threadIdx.x;          // 0..63
    if (fb == NFRAG_) {
        for (int i = l; i < J_; i += 64) out_regions[i] = (float)i;
        for (int i = l; i < R_ * R_; i += 64) {
            const int r1 = i / R_, r2 = i - r1 * R_;
            const unsigned m = ADJMASK[2 * r1] | ADJMASK[2 * r1 + 1];
            out_post[i] = ((m >> (2 * r2)) & 3u) ? 1.0f : 0.0f;
        }
        return;
    }
    const int h   = fb & 1;              // K-half: ci 0..15 or 16..31
    const int tmp = fb >> 1;
    const int kw  = tmp % 3;
    const int e   = tmp / 3;             // 0..69 flat edge index
    int jout = 0;
    while (ADJ_OFF[jout + 1] <= e) ++jout;
    const int nb = ADJ_FLAT[e];
    const int co = l & 31;
    const int g2 = l >> 5;

    union { unsigned short u[8]; uint4 q; } pk;
#pragma unroll
    for (int j = 0; j < 8; ++j) {
        const int ci = h * 16 + g2 * 8 + j;
        const float w = W[((size_t)(jout * COUT_ + co) * (J_ * CIN_) + (nb * CIN_ + ci)) * 3 + kw];
        pk.u[j] = f2bf(w);
    }
    *(uint4*)(wsW + (size_t)fb * 512 + l * 8) = pk.q;
}

// ---------------------------------------------------------------------------
// Main kernel. 8 waves = 4 t-slices x 2 joints; 32x32x16 MFMA. B-slab stored
// PLANE-SEPARATED: 4 ci-planes x 145 rows x 16 B -> stride-16B reads where any
// 8 consecutive lanes cover all 32 banks once (conflict-free, no XOR).
// ---------------------------------------------------------------------------
template<int RGN, int JS, int NB>
__device__ __forceinline__ void nb_step(const unsigned char* __restrict__ ldsB,
                                        const unsigned short* __restrict__ ldsl,
                                        int rtb, int g2, f32x16& acc)
{
    constexpr bool e_ = (kAdjMask[2 * RGN + JS] >> NB) & 1u;
    if constexpr (!e_) return;
    constexpr int SLAB = union_rank(RGN, NB);
    constexpr int LB   = local_base(RGN, JS, NB);
    const unsigned char* bbase = ldsB + SLAB * BSLAB_;

#pragma unroll
    for (int kw = 0; kw < 3; ++kw) {
        const int rt = rtb + kw;                      // 0..129
#pragma unroll
        for (int h = 0; h < 2; ++h) {
            const int s = 2 * h + g2;                 // ci-plane 0..3
            const bf16x8 bv = *(const bf16x8*)(bbase + s * PLSTR_ + rt * 16);
            const bf16x8 a  = *(const bf16x8*)(ldsl + (size_t)(LB + kw * 2 + h) * 512);
            acc = __builtin_amdgcn_mfma_f32_32x32x16_bf16(a, bv, acc, 0, 0, 0);
        }
    }
}

template<int RGN, int JS, int... NBs>
__device__ __forceinline__ void joint_all(std::integer_sequence<int, NBs...>,
                                          const unsigned char* __restrict__ ldsB,
                                          const unsigned short* __restrict__ ldsl,
                                          int rtb, int g2, f32x16& acc)
{
    (nb_step<RGN, JS, NBs>(ldsB, ldsl, rtb, g2, acc), ...);
}

template<int RGN>
__device__ __forceinline__ void run_region(int js,
                                           const unsigned char* __restrict__ ldsB,
                                           const unsigned short* __restrict__ ldsl,
                                           int rtb, int g2, f32x16& acc)
{
    using Seq = std::make_integer_sequence<int, J_>;
    if (js == 0) joint_all<RGN, 0>(Seq{}, ldsB, ldsl, rtb, g2, acc);
    else         joint_all<RGN, 1>(Seq{}, ldsB, ldsl, rtb, g2, acc);
}

__global__ __launch_bounds__(512)
void skel_main(const unsigned short* __restrict__ xT,
               const unsigned short* __restrict__ wsW,
               const float* __restrict__ bias, float* __restrict__ out)
{
    // XCD-chunked swizzle (grid 3072 = 8*384, bijective): the 12 regions of a
    // (b,t-tile) group land on one XCD so shared xT rows stay L2-resident.
    const int i    = blockIdx.x;          // 0..3071
    const int xcd  = i & 7;
    const int slot = i >> 3;              // 0..383
    const int r    = slot % R_;
    const int gi   = slot / R_;           // 0..31
    const int g    = xcd + 8 * gi;        // (b,t-tile) group 0..255
    const int b    = g >> 5;
    const int t0   = (g & 31) * TT_;

    const int tid  = threadIdx.x;
    const int wv   = tid >> 6;            // 0..7
    const int lane = tid & 63;
    const int l31  = lane & 31;
    const int g2   = lane >> 5;
    const int ws   = wv & 3;              // t-slice 0..3
    const int js   = wv >> 2;             // joint select 0/1

    __shared__ __align__(16) unsigned char lds[ALDS_ + 8 * BSLAB_];  // 123,392 B
    unsigned short* ldsA = (unsigned short*)lds;
    unsigned char*  ldsB = lds + ALDS_;

    const int j0 = 2 * r, j1 = 2 * r + 1;

    // --- B-stage: wave w stages union-neighbor w via 9x global_load_lds into
    // the plane-separated slab. Lane l of write L covers linear slab index
    // idx = 64L + l -> plane p = idx/145, row rt = idx%145 (global src remap).
    {
        const int NU = UNION_CNT[r];
        if (wv < NU) {
            const int nb = UNION_NB[r][wv];
            const unsigned short* gb = xT + (size_t)b * T_ * (J_ * CIN_) + nb * CIN_;
            unsigned char* ldst = ldsB + wv * BSLAB_;
#pragma unroll
            for (int L = 0; L < 9; ++L) {
                const int idx = L * 64 + lane;        // 0..575
                const int p   = idx / PLROWS_;        // ci-plane 0..3
                const int rt  = idx - p * PLROWS_;    // row 0..144
                int t = t0 - 1 + rt;
                t = t < 0 ? 0 : (t > T_ - 1 ? T_ - 1 : t);
                const unsigned short* gsrc = gb + (size_t)t * (J_ * CIN_) + p * 8;
                gload_lds16(gsrc, ldst + L * 1024);
            }
        }
    }
    // --- A-stage: coalesced uint4 copy of this region's fragments. ---
    {
        const int n0 = ADJ_OFF[j0 + 1] - ADJ_OFF[j0];
        const int n1 = ADJ_OFF[j1 + 1] - ADJ_OFF[j1];
        const uint4* s0 = (const uint4*)(wsW + (size_t)ADJ_OFF[j0] * 6 * 512);
        const uint4* s1 = (const uint4*)(wsW + (size_t)ADJ_OFF[j1] * 6 * 512);
        uint4* dA = (uint4*)ldsA;
        const int q0 = n0 * 384;           // 1KB frag = 64 uint4
        const int q1 = n1 * 384;
        for (int c = tid; c < q0; c += 512) dA[c] = s0[c];
        for (int c = tid; c < q1; c += 512) dA[q0 + c] = s1[c];
    }
    __syncthreads();                       // drains vmcnt (gload_lds) + lgkm

    // --- SAME-padding: zero the pad row (t=-1 or t=T) in every slab/plane. ---
    if (t0 == 0 || t0 == T_ - TT_) {
        const int zr = (t0 == 0) ? 0 : (TT_ + 1);
        if (tid < 32) {
            const uint4 z = {0u, 0u, 0u, 0u};
            *(uint4*)(ldsB + (tid >> 2) * BSLAB_ + (tid & 3) * PLSTR_ + zr * 16) = z;
        }
        __syncthreads();
    }

    f32x16 acc;
#pragma unroll
    for (int q = 0; q < 16; ++q) acc[q] = 0.0f;

    const unsigned short* ldsl = ldsA + lane * 8;
    const int rtb = ws * 32 + l31;         // local row for kw=0 (t-1 shift)

    switch (r) {
        case 0:  run_region<0>(js, ldsB, ldsl, rtb, g2, acc); break;
        case 1:  run_region<1>(js, ldsB, ldsl, rtb, g2, acc); break;
        case 2:  run_region<2>(js, ldsB, ldsl, rtb, g2, acc); break;
        case 3:  run_region<3>(js, ldsB, ldsl, rtb, g2, acc); break;
        case 4:  run_region<4>(js, ldsB, ldsl, rtb, g2, acc); break;
        case 5:  run_region<5>(js, ldsB, ldsl, rtb, g2, acc); break;
        case 6:  run_region<6>(js, ldsB, ldsl, rtb, g2, acc); break;
        case 7:  run_region<7>(js, ldsB, ldsl, rtb, g2, acc); break;
        case 8:  run_region<8>(js, ldsB, ldsl, rtb, g2, acc); break;
        case 9:  run_region<9>(js, ldsB, ldsl, rtb, g2, acc); break;
        case 10: run_region<10>(js, ldsB, ldsl, rtb, g2, acc); break;
        default: run_region<11>(js, ldsB, ldsl, rtb, g2, acc); break;
    }

    // --- Epilogue. 32x32 D layout [verified m74/m101]: col(t) = lane&31,
    // row(co) = (q&3) + 8*(q>>2) + 4*(lane>>5). Per-joint bias+leakyReLU, then
    // cross-wave pair-mean via LDS scratch (reuses A region after barrier). ---
    const int jw = 2 * r + js;
    f32x4 yv[4];
#pragma unroll
    for (int qq = 0; qq < 4; ++qq) {
#pragma unroll
        for (int qi = 0; qi < 4; ++qi) {
            const int co = 8 * qq + 4 * g2 + qi;
            float y = acc[qq * 4 + qi] + bias[jw * COUT_ + co];
            yv[qq][qi] = (y > 0.f) ? y : 0.2f * y;
        }
    }

    __syncthreads();                       // A region dead; safe to reuse
    float* scr = (float*)lds;              // [ws][qq][lane][4] f32 = 16 KB
    if (js == 1) {
#pragma unroll
        for (int qq = 0; qq < 4; ++qq)
            *(f32x4*)(scr + ws * 4096 + qq * 1024 + lane * 4) = yv[qq];
    }
    __syncthreads();
    if (js == 0) {
#pragma unroll
        for (int qq = 0; qq < 4; ++qq) {
            const f32x4 pv = *(const f32x4*)(scr + ws * 4096 + qq * 1024 + lane * 4);
#pragma unroll
            for (int qi = 0; qi < 4; ++qi) {
                const int co = 8 * qq + 4 * g2 + qi;
                out[((size_t)b * (R_ * COUT_) + r * COUT_ + co) * T_
                    + t0 + ws * 32 + l31] = 0.5f * (yv[qq][qi] + pv[qi]);
            }
        }
    }
}

extern "C" void kernel_launch(void* const* d_in, const int* in_sizes, int n_in,
                              void* d_out, int out_size, void* d_ws, size_t ws_size,
                              hipStream_t stream)
{
    const float* x    = (const float*)d_in[0];
    const float* W    = (const float*)d_in[1];
    const float* bias = (const float*)d_in[2];
    float* out = (float*)d_out;

    unsigned short* xT  = (unsigned short*)d_ws;                 // 48 MiB bf16
    unsigned short* wsW = xT + XT_ELEMS_;                        // +420 KiB frags

    dim3 tgrid(T_ / 256, J_ * CIN_ / 32, B_);
    skel_transpose<<<tgrid, 256, 0, stream>>>(x, xT);

    float* out_regions = out + POOLED_SZ_;
    float* out_post    = out_regions + J_;
    skel_pack<<<NFRAG_ + 1, 64, 0, stream>>>(W, wsW, out_regions, out_post);

    skel_main<<<(T_ / TT_) * R_ * B_, 512, 0, stream>>>(xT, wsW, bias, out);
}

// Round 15
// 71.914 us; speedup vs baseline: 1.3797x; 1.3797x over previous
//
#include <hip/hip_runtime.h>
#include <hip/hip_bf16.h>
#include <utility>

// Problem constants (fixed by the reference setup_inputs()).
#define J_     24
#define CIN_   32
#define COUT_  32
#define B_     8
#define T_     4096
#define R_     12
#define TT_    128                         // t per main-kernel block (4 t-slices x 32t, x2 joints = 8 waves)
#define POOLED_SZ_ (B_ * R_ * COUT_ * T_)  // 12,582,912
#define XT_ELEMS_  ((size_t)B_ * T_ * (J_ * CIN_))   // 25,165,824 bf16
#define NFRAG_     420                     // 70 edges * 3 kw * 2 K-halves
#define PLROWS_    145                     // rows per ci-plane (145*16B = 2320 B)
#define PLSTR_     (PLROWS_ * 16)          // 2320 B plane stride
#define BSLAB_     (4 * PLSTR_)            // 9280 B per neighbor slab
// LDS = B-slabs only: 8 * 9280 = 74,240 B -> 2 blocks/CU co-resident.

typedef float  f32x4  __attribute__((ext_vector_type(4)));
typedef float  f32x16 __attribute__((ext_vector_type(16)));
typedef short  bf16x8 __attribute__((ext_vector_type(8)));
typedef unsigned short us8 __attribute__((ext_vector_type(8)));

// Compile-time adjacency (verified R1/R5): bit n of kAdjMask[i] <=> n in ADJ_LIST[i].
static constexpr unsigned kAdjMask[J_] = {
    0x0000000Fu, 0x00000013u, 0x00000025u, 0x00000049u, 0x00000092u, 0x00000124u,
    0x00000248u, 0x00000490u, 0x00000920u, 0x00007240u, 0x00000480u, 0x00000900u,
    0x00009200u, 0x00012200u, 0x00024200u, 0x00009000u, 0x00052000u, 0x000A4000u,
    0x00150000u, 0x002A0000u, 0x00540000u, 0x00A80000u, 0x00500000u, 0x00A00000u
};
static constexpr int kAdjOff[J_ + 1] = {
    0,4,7,10,13,16,19,22,25,28,33,35,37,40,43,46,48,51,54,57,60,63,66,68,70
};
static constexpr int edge_of(int jout, int nb) {
    return kAdjOff[jout] + __builtin_popcount(kAdjMask[jout] & ((1u << nb) - 1u));
}
// Union-neighborhood helpers.
static constexpr unsigned union_mask(int r) { return kAdjMask[2 * r] | kAdjMask[2 * r + 1]; }
static constexpr int union_rank(int r, int nb) {
    return __builtin_popcount(union_mask(r) & ((1u << nb) - 1u));
}

// Device-side tables for runtime staging / pack kernels.
__device__ __constant__ unsigned int ADJMASK[J_] = {
    0x0000000Fu, 0x00000013u, 0x00000025u, 0x00000049u, 0x00000092u, 0x00000124u,
    0x00000248u, 0x00000490u, 0x00000920u, 0x00007240u, 0x00000480u, 0x00000900u,
    0x00009200u, 0x00012200u, 0x00024200u, 0x00009000u, 0x00052000u, 0x000A4000u,
    0x00150000u, 0x002A0000u, 0x00540000u, 0x00A80000u, 0x00500000u, 0x00A00000u
};
__device__ __constant__ int ADJ_FLAT[70] = {
    0,1,2,3,  0,1,4,  0,2,5,  0,3,6,  1,4,7,  2,5,8,  3,6,9,  4,7,10,  5,8,11,
    6,9,12,13,14,  7,10,  8,11,  9,12,15,  9,13,16,  9,14,17,  12,15,
    13,16,18,  14,17,19,  16,18,20,  17,19,21,  18,20,22,  19,21,23,  20,22,  21,23
};
__device__ __constant__ int ADJ_OFF[J_ + 1] = {
    0,4,7,10,13,16,19,22,25,28,33,35,37,40,43,46,48,51,54,57,60,63,66,68,70
};
// Union walk tables (ascending; verified against kAdjMask ORs).
__device__ __constant__ int UNION_CNT[R_] = {5,5,6,6,8,4,5,5,6,6,6,4};
__device__ __constant__ int UNION_NB[R_][8] = {
    {0,1,2,3,4,0,0,0},      {0,2,3,5,6,0,0,0},      {1,2,4,5,7,8,0,0},
    {3,4,6,7,9,10,0,0},     {5,6,8,9,11,12,13,14},  {7,8,10,11,0,0,0,0},
    {9,12,13,15,16,0,0,0},  {9,12,14,15,17,0,0,0},  {13,14,16,17,18,19,0,0},
    {16,17,18,19,20,21,0,0},{18,19,20,21,22,23,0,0},{20,21,22,23,0,0,0,0}
};

static __device__ __forceinline__ unsigned short f2bf(float f) {
    unsigned u = __float_as_uint(f);
    unsigned r = (u + 0x7fffu + ((u >> 16) & 1u)) >> 16;   // RNE
    return (unsigned short)r;
}

// ---------------------------------------------------------------------------
// Pre-kernel 1: x fp32 [b][768][4096] -> xT bf16 [b][4096][768] via LDS tiles.
// (Already ~HBM-roofline: 148 MB at ~6 TB/s.)
// ---------------------------------------------------------------------------
__global__ __launch_bounds__(256)
void skel_transpose(const float* __restrict__ x, unsigned short* __restrict__ xT)
{
    __shared__ float xs[32][257];
    const int tid = threadIdx.x;
    const int tt0 = blockIdx.x * 256;   // t tile
    const int cg  = blockIdx.y;         // channel group of 32 (0..23)
    const int b   = blockIdx.z;

    const float* xp = x + ((size_t)b * (J_ * CIN_) + cg * 32) * T_ + tt0;
#pragma unroll
    for (int i = 0; i < 8; ++i) {
        const int idx = tid + i * 256;
        const int row = idx >> 6;            // 0..31
        const int c4  = (idx & 63) << 2;     // 0..252
        const float4 v = *(const float4*)(xp + (size_t)row * T_ + c4);
        xs[row][c4 + 0] = v.x; xs[row][c4 + 1] = v.y;
        xs[row][c4 + 2] = v.z; xs[row][c4 + 3] = v.w;
    }
    __syncthreads();

    union { unsigned short u[32]; uint4 q[4]; } pk;
#pragma unroll
    for (int c = 0; c < 32; ++c) pk.u[c] = f2bf(xs[c][tid]);
    unsigned short* dst = xT + ((size_t)b * T_ + tt0 + tid) * (J_ * CIN_) + cg * 32;
#pragma unroll
    for (int k = 0; k < 4; ++k) *(uint4*)(dst + k * 8) = pk.q[k];
}

// ---------------------------------------------------------------------------
// Pre-kernel 2: pack masked W blocks into per-lane 32x32x16 MFMA A-fragments.
// Lane map: m(co) = lane&31; k(ci) = h*16 + (lane>>5)*8 + j  -- SAME
// (lane-group, j)->ci map as the B side, so internal K permutation cancels.
// Block 420 additionally writes the REGIONS / POST_ADJ constant outputs.
// ---------------------------------------------------------------------------
__global__ __launch_bounds__(64)
void skel_pack(const float* __restrict__ W, unsigned short* __restrict__ wsW,
               float* __restrict__ out_regions, float* __restrict__ out_post)
{
    const int fb = blockIdx.x;
    const int l  = threadIdx.x;          // 0..63
    if (fb == NFRAG_) {
        for (int i = l; i < J_; i += 64) out_regions[i] = (float)i;
        for (int i = l; i < R_ * R_; i += 64) {
            const int r1 = i / R_, r2 = i - r1 * R_;
            const unsigned m = ADJMASK[2 * r1] | ADJMASK[2 * r1 + 1];
            out_post[i] = ((m >> (2 * r2)) & 3u) ? 1.0f : 0.0f;
        }
        return;
    }
    const int h   = fb & 1;              // K-half: ci 0..15 or 16..31
    const int tmp = fb >> 1;
    const int kw  = tmp % 3;
    const int e   = tmp / 3;             // 0..69 flat edge index
    int jout = 0;
    while (ADJ_OFF[jout + 1] <= e) ++jout;
    const int nb = ADJ_FLAT[e];
    const int co = l & 31;
    const int g2 = l >> 5;

    union { unsigned short u[8]; uint4 q; } pk;
#pragma unroll
    for (int j = 0; j < 8; ++j) {
        const int ci = h * 16 + g2 * 8 + j;
        const float w = W[((size_t)(jout * COUT_ + co) * (J_ * CIN_) + (nb * CIN_ + ci)) * 3 + kw];
        pk.u[j] = f2bf(w);
    }
    *(uint4*)(wsW + (size_t)fb * 512 + l * 8) = pk.q;
}

// ---------------------------------------------------------------------------
// Main kernel. 8 waves = 4 t-slices x 2 joints; 32x32x16 MFMA. B-slab in LDS
// (plane-separated, conflict-free reads); A-fragments read straight from L2
// (420 KB, XCD-hot, constexpr offsets). LDS = 74,240 B -> 2 blocks/CU so
// block n+1's staging overlaps block n's compute.
// ---------------------------------------------------------------------------
template<int RGN, int JS, int NB>
__device__ __forceinline__ void nb_step(const unsigned char* __restrict__ ldsB,
                                        const unsigned short* __restrict__ wsWl,
                                        int rtb, int g2, f32x16& acc)
{
    constexpr bool e_ = (kAdjMask[2 * RGN + JS] >> NB) & 1u;
    if constexpr (!e_) return;
    constexpr int SLAB = union_rank(RGN, NB);
    constexpr int E    = edge_of(2 * RGN + JS, NB);   // global edge index
    const unsigned char* bbase = ldsB + SLAB * BSLAB_;

#pragma unroll
    for (int kw = 0; kw < 3; ++kw) {
        const int rt = rtb + kw;                      // 0..129
#pragma unroll
        for (int h = 0; h < 2; ++h) {
            const int s = 2 * h + g2;                 // ci-plane 0..3
            const bf16x8 bv = *(const bf16x8*)(bbase + s * PLSTR_ + rt * 16);
            const bf16x8 a  = *(const bf16x8*)(wsWl + (size_t)(E * 6 + kw * 2 + h) * 512);
            acc = __builtin_amdgcn_mfma_f32_32x32x16_bf16(a, bv, acc, 0, 0, 0);
        }
    }
}

template<int RGN, int JS, int... NBs>
__device__ __forceinline__ void joint_all(std::integer_sequence<int, NBs...>,
                                          const unsigned char* __restrict__ ldsB,
                                          const unsigned short* __restrict__ wsWl,
                                          int rtb, int g2, f32x16& acc)
{
    (nb_step<RGN, JS, NBs>(ldsB, wsWl, rtb, g2, acc), ...);
}

template<int RGN>
__device__ __forceinline__ void run_region(int js,
                                           const unsigned char* __restrict__ ldsB,
                                           const unsigned short* __restrict__ wsWl,
                                           int rtb, int g2, f32x16& acc)
{
    using Seq = std::make_integer_sequence<int, J_>;
    if (js == 0) joint_all<RGN, 0>(Seq{}, ldsB, wsWl, rtb, g2, acc);
    else         joint_all<RGN, 1>(Seq{}, ldsB, wsWl, rtb, g2, acc);
}

__global__ __launch_bounds__(512, 4)
void skel_main(const unsigned short* __restrict__ xT,
               const unsigned short* __restrict__ wsW,
               const float* __restrict__ bias, float* __restrict__ out)
{
    // XCD-chunked swizzle (grid 3072 = 8*384, bijective): the 12 regions of a
    // (b,t-tile) group land on one XCD so shared xT rows stay L2-resident.
    const int i    = blockIdx.x;          // 0..3071
    const int xcd  = i & 7;
    const int slot = i >> 3;              // 0..383
    const int r    = slot % R_;
    const int gi   = slot / R_;           // 0..31
    const int g    = xcd + 8 * gi;        // (b,t-tile) group 0..255
    const int b    = g >> 5;
    const int t0   = (g & 31) * TT_;

    const int tid  = threadIdx.x;
    const int wv   = tid >> 6;            // 0..7
    const int lane = tid & 63;
    const int l31  = lane & 31;
    const int g2   = lane >> 5;
    const int ws   = wv & 3;              // t-slice 0..3
    const int js   = wv >> 2;             // joint select 0/1

    __shared__ __align__(16) unsigned char lds[8 * BSLAB_];   // 74,240 B
    unsigned char* ldsB = lds;

    // --- B-stage: wave w stages union-neighbor w. Reg-staged: coalesced
    // global loads (4 lanes x 16B per row, 16 rows per step), zero-fill for
    // SAME-pad rows, ds_write_b128 into the plane-separated layout. ---
    {
        const int NU = UNION_CNT[r];
        if (wv < NU) {
            const int nb = UNION_NB[r][wv];
            const unsigned short* gb = xT + (size_t)b * T_ * (J_ * CIN_) + nb * CIN_;
            unsigned char* ldst = ldsB + wv * BSLAB_;
            const int p  = lane & 3;       // ci-plane
            const int r0 = lane >> 2;      // row within step
            us8 v[9];
#pragma unroll
            for (int L = 0; L < 9; ++L) {
                const int rt = L * 16 + r0;            // 0..143 (need 0..129)
                const int t  = t0 - 1 + rt;
                const int tc = t < 0 ? 0 : (t > T_ - 1 ? T_ - 1 : t);
                v[L] = *(const us8*)(gb + (size_t)tc * (J_ * CIN_) + p * 8);
                if ((unsigned)t >= (unsigned)T_) {
                    const us8 z = {0, 0, 0, 0, 0, 0, 0, 0};
                    v[L] = z;
                }
            }
#pragma unroll
            for (int L = 0; L < 9; ++L) {
                const int rt = L * 16 + r0;
                *(us8*)(ldst + p * PLSTR_ + rt * 16) = v[L];
            }
        }
    }
    __syncthreads();

    f32x16 acc;
#pragma unroll
    for (int q = 0; q < 16; ++q) acc[q] = 0.0f;

    const unsigned short* wsWl = wsW + lane * 8;
    const int rtb = ws * 32 + l31;         // local row for kw=0 (t-1 shift)

    switch (r) {
        case 0:  run_region<0>(js, ldsB, wsWl, rtb, g2, acc); break;
        case 1:  run_region<1>(js, ldsB, wsWl, rtb, g2, acc); break;
        case 2:  run_region<2>(js, ldsB, wsWl, rtb, g2, acc); break;
        case 3:  run_region<3>(js, ldsB, wsWl, rtb, g2, acc); break;
        case 4:  run_region<4>(js, ldsB, wsWl, rtb, g2, acc); break;
        case 5:  run_region<5>(js, ldsB, wsWl, rtb, g2, acc); break;
        case 6:  run_region<6>(js, ldsB, wsWl, rtb, g2, acc); break;
        case 7:  run_region<7>(js, ldsB, wsWl, rtb, g2, acc); break;
        case 8:  run_region<8>(js, ldsB, wsWl, rtb, g2, acc); break;
        case 9:  run_region<9>(js, ldsB, wsWl, rtb, g2, acc); break;
        case 10: run_region<10>(js, ldsB, wsWl, rtb, g2, acc); break;
        default: run_region<11>(js, ldsB, wsWl, rtb, g2, acc); break;
    }

    // --- Epilogue. 32x32 D layout [verified m74/m101/R13]: col(t) = lane&31,
    // row(co) = (q&3) + 8*(q>>2) + 4*(lane>>5). Per-joint bias+leakyReLU, then
    // cross-wave pair-mean via LDS scratch (reuses B region after barrier). ---
    const int jw = 2 * r + js;
    f32x4 yv[4];
#pragma unroll
    for (int qq = 0; qq < 4; ++qq) {
#pragma unroll
        for (int qi = 0; qi < 4; ++qi) {
            const int co = 8 * qq + 4 * g2 + qi;
            float y = acc[qq * 4 + qi] + bias[jw * COUT_ + co];
            yv[qq][qi] = (y > 0.f) ? y : 0.2f * y;
        }
    }

    __syncthreads();                       // B region dead; safe to reuse
    float* scr = (float*)lds;              // [ws][qq][lane][4] f32 = 64 KB
    if (js == 1) {
#pragma unroll
        for (int qq = 0; qq < 4; ++qq)
            *(f32x4*)(scr + ws * 4096 + qq * 1024 + lane * 4) = yv[qq];
    }
    __syncthreads();
    if (js == 0) {
#pragma unroll
        for (int qq = 0; qq < 4; ++qq) {
            const f32x4 pv = *(const f32x4*)(scr + ws * 4096 + qq * 1024 + lane * 4);
#pragma unroll
            for (int qi = 0; qi < 4; ++qi) {
                const int co = 8 * qq + 4 * g2 + qi;
                out[((size_t)b * (R_ * COUT_) + r * COUT_ + co) * T_
                    + t0 + ws * 32 + l31] = 0.5f * (yv[qq][qi] + pv[qi]);
            }
        }
    }
}

extern "C" void kernel_launch(void* const* d_in, const int* in_sizes, int n_in,
                              void* d_out, int out_size, void* d_ws, size_t ws_size,
                              hipStream_t stream)
{
    const float* x    = (const float*)d_in[0];
    const float* W    = (const float*)d_in[1];
    const float* bias = (const float*)d_in[2];
    float* out = (float*)d_out;

    unsigned short* xT  = (unsigned short*)d_ws;                 // 48 MiB bf16
    unsigned short* wsW = xT + XT_ELEMS_;                        // +420 KiB frags

    dim3 tgrid(T_ / 256, J_ * CIN_ / 32, B_);
    skel_transpose<<<tgrid, 256, 0, stream>>>(x, xT);

    float* out_regions = out + POOLED_SZ_;
    float* out_post    = out_regions + J_;
    skel_pack<<<NFRAG_ + 1, 64, 0, stream>>>(W, wsW, out_regions, out_post);

    skel_main<<<(T_ / TT_) * R_ * B_, 512, 0, stream>>>(xT, wsW, bias, out);
}